// Round 11
// baseline (96.578 us; speedup 1.0000x reference)
//
#include <hip/hip_runtime.h>
#include <hip/hip_bf16.h>

typedef __bf16 bf16x8 __attribute__((ext_vector_type(8)));
typedef float  f32x4  __attribute__((ext_vector_type(4)));

#define SEQ   1024
#define BATCH 8
#define DIMM  512
#define HEADS 8
#define DHEAD 64
#define TRIPLE 1536
#define MROWS (BATCH*SEQ)   // 8192

#define GLOAD_LDS16(g, l) __builtin_amdgcn_global_load_lds( \
    (const __attribute__((address_space(1))) void*)(const void*)(g), \
    (__attribute__((address_space(3))) void*)(void*)(l), 16, 0, 0)

// ---------------- merged |w| partial sums ----------------
__global__ __launch_bounds__(256) void absum_all(const float* __restrict__ w1,
                                                 const float* __restrict__ w2,
                                                 float* __restrict__ part) {
    const int bid = blockIdx.x, tid = threadIdx.x;
    float s = 0.f;
    if (bid < 256) {
        const float4* p = (const float4*)w1;
        for (int i = bid * 256 + tid; i < 196608; i += 65536) {
            float4 v = p[i];
            s += fabsf(v.x) + fabsf(v.y) + fabsf(v.z) + fabsf(v.w);
        }
    } else {
        const float4* p = (const float4*)w2;
        for (int i = (bid - 256) * 256 + tid; i < 65536; i += 16384) {
            float4 v = p[i];
            s += fabsf(v.x) + fabsf(v.y) + fabsf(v.z) + fabsf(v.w);
        }
    }
    for (int o = 32; o; o >>= 1) s += __shfl_down(s, o);
    __shared__ float red[4];
    if (!(tid & 63)) red[tid >> 6] = s;
    __syncthreads();
    if (tid == 0) part[bid] = red[0] + red[1] + red[2] + red[3];
}

__global__ void finalize_scales(const float* __restrict__ part, float* __restrict__ scales) {
    int t = threadIdx.x;                 // 256 threads
    float v1 = part[t];
    float v2 = (t < 64) ? part[256 + t] : 0.f;
    for (int o = 32; o; o >>= 1) { v1 += __shfl_down(v1, o); v2 += __shfl_down(v2, o); }
    __shared__ float r1[4], r2[4];
    int lane = t & 63, wv = t >> 6;
    if (!lane) { r1[wv] = v1; r2[wv] = v2; }
    __syncthreads();
    if (t == 0) {
        scales[0] = (r1[0] + r1[1] + r1[2] + r1[3]) / 786432.0f;   // 1536*512
        scales[1] = (r2[0] + r2[1] + r2[2] + r2[3]) / 262144.0f;   // 512*512
    }
}

// ---------------- merged ternary quantize -> bf16 ----------------
__global__ __launch_bounds__(256) void quant_all(const float* __restrict__ w1,
                                                 const float* __restrict__ w2,
                                                 const float* __restrict__ scp,
                                                 __bf16* __restrict__ o1,
                                                 __bf16* __restrict__ o2) {
    const int bid = blockIdx.x;
    const float* w; __bf16* o; float s; int idx;
    if (bid < 768) { w = w1; o = o1; s = scp[0]; idx = (bid * 256 + threadIdx.x) * 4; }
    else           { w = w2; o = o2; s = scp[1]; idx = ((bid - 768) * 256 + threadIdx.x) * 4; }
    const float inv = 1.f / (s + 1e-6f);
    float4 v = *reinterpret_cast<const float4*>(w + idx);
    o[idx + 0] = (__bf16)(rintf(fminf(1.f, fmaxf(-1.f, v.x * inv))) * s);
    o[idx + 1] = (__bf16)(rintf(fminf(1.f, fmaxf(-1.f, v.y * inv))) * s);
    o[idx + 2] = (__bf16)(rintf(fminf(1.f, fmaxf(-1.f, v.z * inv))) * s);
    o[idx + 3] = (__bf16)(rintf(fminf(1.f, fmaxf(-1.f, v.w * inv))) * s);
}

// ---------------- wave-per-row layernorm (row = 512), output bf16 ----------------
template<typename TIN>
__global__ __launch_bounds__(256) void ln_fast(const TIN* __restrict__ x,
                                               const float* __restrict__ g,
                                               const float* __restrict__ bta,
                                               __bf16* __restrict__ y) {
    const int row = blockIdx.x * 4 + (threadIdx.x >> 6);
    const int lane = threadIdx.x & 63;
    float v[8];
    if constexpr (sizeof(TIN) == 4) {
        const float4* xr = (const float4*)((const float*)x + (size_t)row * DIMM + lane * 8);
        float4 a = xr[0], bq = xr[1];
        v[0] = a.x; v[1] = a.y; v[2] = a.z; v[3] = a.w;
        v[4] = bq.x; v[5] = bq.y; v[6] = bq.z; v[7] = bq.w;
    } else {
        bf16x8 a = *reinterpret_cast<const bf16x8*>((const __bf16*)x + (size_t)row * DIMM + lane * 8);
#pragma unroll
        for (int e = 0; e < 8; ++e) v[e] = (float)a[e];
    }
    float s = 0.f, sq = 0.f;
#pragma unroll
    for (int e = 0; e < 8; ++e) { s += v[e]; sq += v[e] * v[e]; }
    for (int o = 32; o; o >>= 1) { s += __shfl_xor(s, o); sq += __shfl_xor(sq, o); }
    const float mu = s * (1.f / DIMM);
    const float invs = rsqrtf(sq * (1.f / DIMM) - mu * mu + 1e-5f);
    const float4* gp = (const float4*)(g + lane * 8);
    const float4* bp = (const float4*)(bta + lane * 8);
    float4 g0 = gp[0], g1 = gp[1], b0 = bp[0], b1 = bp[1];
    float o_[8] = {
        (v[0] - mu) * invs * g0.x + b0.x, (v[1] - mu) * invs * g0.y + b0.y,
        (v[2] - mu) * invs * g0.z + b0.z, (v[3] - mu) * invs * g0.w + b0.w,
        (v[4] - mu) * invs * g1.x + b1.x, (v[5] - mu) * invs * g1.y + b1.y,
        (v[6] - mu) * invs * g1.z + b1.z, (v[7] - mu) * invs * g1.w + b1.w };
    uint4 st;
    asm("v_cvt_pk_bf16_f32 %0, %1, %2" : "=v"(st.x) : "v"(o_[0]), "v"(o_[1]));
    asm("v_cvt_pk_bf16_f32 %0, %1, %2" : "=v"(st.y) : "v"(o_[2]), "v"(o_[3]));
    asm("v_cvt_pk_bf16_f32 %0, %1, %2" : "=v"(st.z) : "v"(o_[4]), "v"(o_[5]));
    asm("v_cvt_pk_bf16_f32 %0, %1, %2" : "=v"(st.w) : "v"(o_[6]), "v"(o_[7]));
    *reinterpret_cast<uint4*>(y + (size_t)row * DIMM + lane * 8) = st;
}

// ---------------- LDS-staged MFMA GEMM (round-6 exact: no swizzle) ----------------
template<int NCOLS, bool BIAS, bool OUT_F32>
__global__ __launch_bounds__(256) void gemm_lds(const __bf16* __restrict__ A,
                                                const __bf16* __restrict__ Wt,
                                                const float* __restrict__ bias,
                                                __bf16* __restrict__ outb,
                                                float* __restrict__ outf) {
    const int K = DIMM;
    __shared__ __align__(16) __bf16 As[2][4096];
    __shared__ __align__(16) __bf16 Bs[2][4096];

    const int tid = threadIdx.x;
    const int w = tid >> 6, lane = tid & 63;
    const int m = lane & 15, g = lane >> 4;
    const int mi = w >> 1, ni = w & 1;

    const int trow = tid >> 2;
    const int tc = tid & 3;
    const int sc = (tc ^ ((trow >> 1) & 3)) * 8;
    const __bf16* a0 = A  + (size_t)(blockIdx.x * 128 + trow) * K + sc;
    const __bf16* a1 = a0 + (size_t)64 * K;
    const __bf16* b0 = Wt + (size_t)(blockIdx.y * 128 + trow) * K + sc;
    const __bf16* b1 = b0 + (size_t)64 * K;

    f32x4 acc[4][4] = {};

    GLOAD_LDS16(a0, (char*)As[0] + tid * 16);
    GLOAD_LDS16(a1, (char*)As[0] + 4096 + tid * 16);
    GLOAD_LDS16(b0, (char*)Bs[0] + tid * 16);
    GLOAD_LDS16(b1, (char*)Bs[0] + 4096 + tid * 16);

    int cur = 0;
    for (int k0 = 0; k0 < K; k0 += 32) {
        __syncthreads();
        if (k0 + 32 < K) {
            GLOAD_LDS16(a0 + k0 + 32, (char*)As[cur ^ 1] + tid * 16);
            GLOAD_LDS16(a1 + k0 + 32, (char*)As[cur ^ 1] + 4096 + tid * 16);
            GLOAD_LDS16(b0 + k0 + 32, (char*)Bs[cur ^ 1] + tid * 16);
            GLOAD_LDS16(b1 + k0 + 32, (char*)Bs[cur ^ 1] + 4096 + tid * 16);
        }

        const char* Ab = (const char*)As[cur];
        const char* Bb = (const char*)Bs[cur];
        bf16x8 af[4], bfr[4];
#pragma unroll
        for (int i = 0; i < 4; ++i) {
            const int ra = mi * 64 + i * 16 + m;
            af[i] = *reinterpret_cast<const bf16x8*>(Ab + ra * 64 + ((g ^ ((ra >> 1) & 3)) << 4));
        }
#pragma unroll
        for (int j = 0; j < 4; ++j) {
            const int rb = ni * 64 + j * 16 + m;
            bfr[j] = *reinterpret_cast<const bf16x8*>(Bb + rb * 64 + ((g ^ ((rb >> 1) & 3)) << 4));
        }
#pragma unroll
        for (int i = 0; i < 4; ++i)
#pragma unroll
            for (int j = 0; j < 4; ++j)
                acc[i][j] = __builtin_amdgcn_mfma_f32_16x16x32_bf16(af[i], bfr[j], acc[i][j], 0, 0, 0);
        cur ^= 1;
    }

    const int orow0 = blockIdx.x * 128 + mi * 64 + g * 4;
    const int ocol0 = blockIdx.y * 128 + ni * 64;
#pragma unroll
    for (int i = 0; i < 4; ++i)
#pragma unroll
        for (int j = 0; j < 4; ++j)
#pragma unroll
            for (int r = 0; r < 4; ++r) {
                int row = orow0 + i * 16 + r;
                int col = ocol0 + j * 16 + m;
                float v = acc[i][j][r];
                if (BIAS) v += bias[col];
                if (OUT_F32) outf[(size_t)row * NCOLS + col] = v;
                else         outb[(size_t)row * NCOLS + col] = (__bf16)v;
            }
}

// ---------------- MFMA flash attention, KVBLK=128 as two verified 64-key sub-tiles ----------------
// grid (8 q-blocks of 128 rows, 64 b*h); 256 threads = 4 waves, 32 q-rows/wave.
// Sync structure = round-6 exact (2 barriers per iteration); iteration now covers
// two sub-tiles A (keys 0-63) and B (keys 64-127), each staged/computed with the
// round-6 verified code. Joint online softmax across both sub-tiles.
__global__ __launch_bounds__(256, 2) void attn_mfma(const __bf16* __restrict__ qkv,
                                                    __bf16* __restrict__ out) {
    const int qt = blockIdx.x, bh = blockIdx.y;
    const int b = bh >> 3, h = bh & 7;
    const int tid = threadIdx.x;
    const int w = tid >> 6, lane = tid & 63;
    const int g = lane >> 4, m = lane & 15;

    __shared__ __align__(16) __bf16 KbA[4096];     // [64 key][64 d], chunk c at c^(key&7)
    __shared__ __align__(16) __bf16 KbB[4096];
    __shared__ __align__(16) __bf16 VtA[4096];     // [64 d][64 key], chunk c at c^((d>>3)^(d&7))
    __shared__ __align__(16) __bf16 VtB[4096];
    __shared__ __align__(16) __bf16 PlA[4][2048];  // per-wave [32 q][64 key], chunk c at c^(q&7)
    __shared__ __align__(16) __bf16 PlB[4][2048];

    bf16x8 qf[2][2];
    {
        const __bf16* qp = qkv + (size_t)(b * SEQ + qt * 128 + w * 32 + m) * TRIPLE + h * 64 + g * 8;
#pragma unroll
        for (int hf = 0; hf < 2; ++hf) {
            qf[hf][0] = *reinterpret_cast<const bf16x8*>(qp + (size_t)hf * 16 * TRIPLE);
            qf[hf][1] = *reinterpret_cast<const bf16x8*>(qp + (size_t)hf * 16 * TRIPLE + 32);
#pragma unroll
            for (int e = 0; e < 8; ++e) {
                qf[hf][0][e] = (__bf16)((float)qf[hf][0][e] * 0.125f);
                qf[hf][1][e] = (__bf16)((float)qf[hf][1][e] * 0.125f);
            }
        }
    }

    const int srow = tid >> 3;          // 0..31
    const int sc   = tid & 7;           // 0..7
    const size_t rbase = (size_t)(b * SEQ + srow) * TRIPLE + h * 64 + sc * 8;
    const __bf16* kp = qkv + rbase + DIMM;       // K row srow (+32/+64/+96 below)
    const __bf16* vp = qkv + rbase + 2 * DIMM;
    const int kstep = 128 * TRIPLE;              // tile-pair stride

    char* kwA0 = (char*)KbA + srow * 128 + ((sc ^ (srow & 7)) << 4);
    char* kwA1 = kwA0 + 32 * 128;
    char* kwB0 = (char*)KbB + srow * 128 + ((sc ^ (srow & 7)) << 4);
    char* kwB1 = kwB0 + 32 * 128;

    f32x4 oa[2][4] = {};
    float mrun[2] = {-1e30f, -1e30f}, lrun[2] = {0.f, 0.f};

    // current tile-pair registers (rows srow, srow+32, srow+64, srow+96)
    uint4 kA0 = *reinterpret_cast<const uint4*>(kp);
    uint4 kA1 = *reinterpret_cast<const uint4*>(kp + (size_t)32 * TRIPLE);
    uint4 kB0 = *reinterpret_cast<const uint4*>(kp + (size_t)64 * TRIPLE);
    uint4 kB1 = *reinterpret_cast<const uint4*>(kp + (size_t)96 * TRIPLE);
    uint4 vA0 = *reinterpret_cast<const uint4*>(vp);
    uint4 vA1 = *reinterpret_cast<const uint4*>(vp + (size_t)32 * TRIPLE);
    uint4 vB0 = *reinterpret_cast<const uint4*>(vp + (size_t)64 * TRIPLE);
    uint4 vB1 = *reinterpret_cast<const uint4*>(vp + (size_t)96 * TRIPLE);
    uint4 nkA0 = {}, nkA1 = {}, nkB0 = {}, nkB1 = {};
    uint4 nvA0 = {}, nvA1 = {}, nvB0 = {}, nvB1 = {};

    for (int t = 0; t < 8; ++t) {
        __syncthreads();   // all waves done reading previous tile-pair

        // ---- stage sub-tile A (round-6 verbatim) ----
        *reinterpret_cast<bf16x8*>(kwA0) = *reinterpret_cast<bf16x8*>(&kA0);
        *reinterpret_cast<bf16x8*>(kwA1) = *reinterpret_cast<bf16x8*>(&kA1);
        {
            bf16x8 va = *reinterpret_cast<bf16x8*>(&vA0);
            bf16x8 vb = *reinterpret_cast<bf16x8*>(&vA1);
#pragma unroll
            for (int e = 0; e < 8; ++e) {
                const int dro = (sc * 8 + e) * 128;
                const int sw = ((sc ^ e) & 7) << 4;
                *(__bf16*)((char*)VtA + dro + ((srow * 2) ^ sw))        = va[e];
                *(__bf16*)((char*)VtA + dro + (((srow + 32) * 2) ^ sw)) = vb[e];
            }
        }
        // ---- stage sub-tile B (same code, B buffers) ----
        *reinterpret_cast<bf16x8*>(kwB0) = *reinterpret_cast<bf16x8*>(&kB0);
        *reinterpret_cast<bf16x8*>(kwB1) = *reinterpret_cast<bf16x8*>(&kB1);
        {
            bf16x8 va = *reinterpret_cast<bf16x8*>(&vB0);
            bf16x8 vb = *reinterpret_cast<bf16x8*>(&vB1);
#pragma unroll
            for (int e = 0; e < 8; ++e) {
                const int dro = (sc * 8 + e) * 128;
                const int sw = ((sc ^ e) & 7) << 4;
                *(__bf16*)((char*)VtB + dro + ((srow * 2) ^ sw))        = va[e];
                *(__bf16*)((char*)VtB + dro + (((srow + 32) * 2) ^ sw)) = vb[e];
            }
        }
        __syncthreads();   // tile-pair visible

        if (t < 7) {       // prefetch next tile-pair (overlaps compute)
            const __bf16* kn = kp + (size_t)(t + 1) * kstep;
            const __bf16* vn = vp + (size_t)(t + 1) * kstep;
            nkA0 = *reinterpret_cast<const uint4*>(kn);
            nkA1 = *reinterpret_cast<const uint4*>(kn + (size_t)32 * TRIPLE);
            nkB0 = *reinterpret_cast<const uint4*>(kn + (size_t)64 * TRIPLE);
            nkB1 = *reinterpret_cast<const uint4*>(kn + (size_t)96 * TRIPLE);
            nvA0 = *reinterpret_cast<const uint4*>(vn);
            nvA1 = *reinterpret_cast<const uint4*>(vn + (size_t)32 * TRIPLE);
            nvB0 = *reinterpret_cast<const uint4*>(vn + (size_t)64 * TRIPLE);
            nvB1 = *reinterpret_cast<const uint4*>(vn + (size_t)96 * TRIPLE);
        }

        // ---- S^T = K @ Q^T on both sub-tiles ----
        f32x4 saA[2][4], saB[2][4];
#pragma unroll
        for (int hf = 0; hf < 2; ++hf)
#pragma unroll
            for (int i = 0; i < 4; ++i) {
                saA[hf][i] = (f32x4){0.f, 0.f, 0.f, 0.f};
                saB[hf][i] = (f32x4){0.f, 0.f, 0.f, 0.f};
            }
#pragma unroll
        for (int kc = 0; kc < 2; ++kc) {
            const int cp = ((kc * 4 + g) ^ (m & 7)) << 4;
#pragma unroll
            for (int i = 0; i < 4; ++i) {
                bf16x8 kfA = *reinterpret_cast<const bf16x8*>((const char*)KbA + (i * 16 + m) * 128 + cp);
                bf16x8 kfB = *reinterpret_cast<const bf16x8*>((const char*)KbB + (i * 16 + m) * 128 + cp);
                saA[0][i] = __builtin_amdgcn_mfma_f32_16x16x32_bf16(kfA, qf[0][kc], saA[0][i], 0, 0, 0);
                saA[1][i] = __builtin_amdgcn_mfma_f32_16x16x32_bf16(kfA, qf[1][kc], saA[1][i], 0, 0, 0);
                saB[0][i] = __builtin_amdgcn_mfma_f32_16x16x32_bf16(kfB, qf[0][kc], saB[0][i], 0, 0, 0);
                saB[1][i] = __builtin_amdgcn_mfma_f32_16x16x32_bf16(kfB, qf[1][kc], saB[1][i], 0, 0, 0);
            }
        }

        // ---- joint online softmax per half + P pack/store (both sub-tiles) ----
        char* pwA = (char*)PlA[w] + m * 128;
        char* pwB = (char*)PlB[w] + m * 128;
        const int psw = (m & 7) << 4;
#pragma unroll
        for (int hf = 0; hf < 2; ++hf) {
            float mx = -1e30f;
#pragma unroll
            for (int i = 0; i < 4; ++i)
#pragma unroll
                for (int r = 0; r < 4; ++r) {
                    mx = fmaxf(mx, saA[hf][i][r]);
                    mx = fmaxf(mx, saB[hf][i][r]);
                }
            mx = fmaxf(mx, __shfl_xor(mx, 16));
            mx = fmaxf(mx, __shfl_xor(mx, 32));
            const float mnew = fmaxf(mrun[hf], mx);
            float pA[4][4], pB[4][4];
            float ps = 0.f;
#pragma unroll
            for (int i = 0; i < 4; ++i)
#pragma unroll
                for (int r = 0; r < 4; ++r) {
                    pA[i][r] = __expf(saA[hf][i][r] - mnew);
                    pB[i][r] = __expf(saB[hf][i][r] - mnew);
                    ps += pA[i][r] + pB[i][r];
                }
            ps += __shfl_xor(ps, 16);
            ps += __shfl_xor(ps, 32);
            const float al = __expf(mrun[hf] - mnew);
            mrun[hf] = mnew;
            lrun[hf] = lrun[hf] * al + ps;
#pragma unroll
            for (int i = 0; i < 4; ++i)
#pragma unroll
                for (int r = 0; r < 4; ++r) oa[hf][i][r] *= al;
#pragma unroll
            for (int i = 0; i < 4; ++i) {
                uint2 pka, pkb;
                asm("v_cvt_pk_bf16_f32 %0, %1, %2" : "=v"(pka.x) : "v"(pA[i][0]), "v"(pA[i][1]));
                asm("v_cvt_pk_bf16_f32 %0, %1, %2" : "=v"(pka.y) : "v"(pA[i][2]), "v"(pA[i][3]));
                asm("v_cvt_pk_bf16_f32 %0, %1, %2" : "=v"(pkb.x) : "v"(pB[i][0]), "v"(pB[i][1]));
                asm("v_cvt_pk_bf16_f32 %0, %1, %2" : "=v"(pkb.y) : "v"(pB[i][2]), "v"(pB[i][3]));
                *reinterpret_cast<uint2*>(pwA + hf * 16 * 128 + ((i * 32 + g * 8) ^ psw)) = pka;
                *reinterpret_cast<uint2*>(pwB + hf * 16 * 128 + ((i * 32 + g * 8) ^ psw)) = pkb;
            }
        }

        // ---- P fragments ----
        bf16x8 pfA[2][2], pfB[2][2];
#pragma unroll
        for (int hf = 0; hf < 2; ++hf)
#pragma unroll
            for (int kc = 0; kc < 2; ++kc) {
                pfA[hf][kc] = *reinterpret_cast<const bf16x8*>(
                    pwA + hf * 16 * 128 + ((kc * 64 + g * 16) ^ psw));
                pfB[hf][kc] = *reinterpret_cast<const bf16x8*>(
                    pwB + hf * 16 * 128 + ((kc * 64 + g * 16) ^ psw));
            }

        // ---- O^T += V^T @ P^T (both sub-tiles) ----
#pragma unroll
        for (int kc = 0; kc < 2; ++kc)
#pragma unroll
            for (int i = 0; i < 4; ++i) {
                const int sv = ((i * 2 + (m >> 3)) ^ (m & 7)) & 7;
                bf16x8 vfA = *reinterpret_cast<const bf16x8*>(
                    (const char*)VtA + (i * 16 + m) * 128 + (((kc * 4 + g) ^ sv) << 4));
                bf16x8 vfB = *reinterpret_cast<const bf16x8*>(
                    (const char*)VtB + (i * 16 + m) * 128 + (((kc * 4 + g) ^ sv) << 4));
                oa[0][i] = __builtin_amdgcn_mfma_f32_16x16x32_bf16(vfA, pfA[0][kc], oa[0][i], 0, 0, 0);
                oa[1][i] = __builtin_amdgcn_mfma_f32_16x16x32_bf16(vfA, pfA[1][kc], oa[1][i], 0, 0, 0);
                oa[0][i] = __builtin_amdgcn_mfma_f32_16x16x32_bf16(vfB, pfB[0][kc], oa[0][i], 0, 0, 0);
                oa[1][i] = __builtin_amdgcn_mfma_f32_16x16x32_bf16(vfB, pfB[1][kc], oa[1][i], 0, 0, 0);
            }

        kA0 = nkA0; kA1 = nkA1; kB0 = nkB0; kB1 = nkB1;
        vA0 = nvA0; vA1 = nvA1; vB0 = nvB0; vB1 = nvB1;
    }

    // ---- epilogue (round-6 verbatim) ----
#pragma unroll
    for (int hf = 0; hf < 2; ++hf) {
        const float inv = 1.0f / lrun[hf];
        unsigned int* orow = (unsigned int*)(out +
            (size_t)(b * SEQ + qt * 128 + w * 32 + hf * 16 + m) * DIMM + h * 64);
#pragma unroll
        for (int i = 0; i < 4; ++i)
#pragma unroll
            for (int rp = 0; rp < 2; ++rp) {
                float o0 = oa[hf][i][2 * rp] * inv, o1 = oa[hf][i][2 * rp + 1] * inv;
                unsigned int pk;
                asm("v_cvt_pk_bf16_f32 %0, %1, %2" : "=v"(pk) : "v"(o0), "v"(o1));
                orow[i * 8 + g * 2 + rp] = pk;
            }
    }
}

// ---------------- launch ----------------
extern "C" void kernel_launch(void* const* d_in, const int* in_sizes, int n_in,
                              void* d_out, int out_size, void* d_ws, size_t ws_size,
                              hipStream_t stream) {
    const float* x     = (const float*)d_in[0];
    const float* g1    = (const float*)d_in[1];
    const float* b1    = (const float*)d_in[2];
    const float* W_qkv = (const float*)d_in[3];
    const float* g2    = (const float*)d_in[4];
    const float* b2    = (const float*)d_in[5];
    const float* W_out = (const float*)d_in[6];
    const float* b_out = (const float*)d_in[7];
    float* out = (float*)d_out;

    char* ws = (char*)d_ws;
    float* part   = (float*)(ws);                                // 320 floats
    float* scales = (float*)(ws + 2048);
    __bf16* Wq1 = (__bf16*)(ws + 4096);                          // [1536,512]
    __bf16* Wq2 = (__bf16*)(ws + 4096 + 1572864);                // [512,512]
    __bf16* Xln = (__bf16*)(ws + 4096 + 1572864 + 524288);       // [8192,512] (reused for LN2 out)
    __bf16* QKV = (__bf16*)(ws + 4096 + 1572864 + 524288 + 8388608);            // [8192,1536]
    __bf16* AO  = (__bf16*)(ws + 4096 + 1572864 + 524288 + 8388608 + 25165824); // [8192,512]

    absum_all<<<320, 256, 0, stream>>>(W_qkv, W_out, part);
    finalize_scales<<<1, 256, 0, stream>>>(part, scales);
    quant_all<<<1024, 256, 0, stream>>>(W_qkv, W_out, scales, Wq1, Wq2);
    ln_fast<float><<<MROWS / 4, 256, 0, stream>>>(x, g1, b1, Xln);
    gemm_lds<TRIPLE, false, false><<<dim3(64, 12), 256, 0, stream>>>(Xln, Wq1, nullptr, QKV, nullptr);
    attn_mfma<<<dim3(8, 64), 256, 0, stream>>>(QKV, AO);
    ln_fast<__bf16><<<MROWS / 4, 256, 0, stream>>>(AO, g2, b2, Xln);
    gemm_lds<DIMM, true, true><<<dim3(64, 4), 256, 0, stream>>>(Xln, Wq2, b_out, nullptr, out);
}

// Round 12
// 89.860 us; speedup vs baseline: 1.0748x; 1.0748x over previous
//
#include <hip/hip_runtime.h>
#include <hip/hip_bf16.h>

typedef __bf16 bf16x8 __attribute__((ext_vector_type(8)));
typedef float  f32x4  __attribute__((ext_vector_type(4)));

#define SEQ   1024
#define BATCH 8
#define DIMM  512
#define HEADS 8
#define DHEAD 64
#define TRIPLE 1536
#define MROWS (BATCH*SEQ)   // 8192

#define GLOAD_LDS16(g, l) __builtin_amdgcn_global_load_lds( \
    (const __attribute__((address_space(1))) void*)(const void*)(g), \
    (__attribute__((address_space(3))) void*)(void*)(l), 16, 0, 0)

// ---------------- merged |w| partial sums ----------------
__global__ __launch_bounds__(256) void absum_all(const float* __restrict__ w1,
                                                 const float* __restrict__ w2,
                                                 float* __restrict__ part) {
    const int bid = blockIdx.x, tid = threadIdx.x;
    float s = 0.f;
    if (bid < 256) {
        const float4* p = (const float4*)w1;
        for (int i = bid * 256 + tid; i < 196608; i += 65536) {
            float4 v = p[i];
            s += fabsf(v.x) + fabsf(v.y) + fabsf(v.z) + fabsf(v.w);
        }
    } else {
        const float4* p = (const float4*)w2;
        for (int i = (bid - 256) * 256 + tid; i < 65536; i += 16384) {
            float4 v = p[i];
            s += fabsf(v.x) + fabsf(v.y) + fabsf(v.z) + fabsf(v.w);
        }
    }
    for (int o = 32; o; o >>= 1) s += __shfl_down(s, o);
    __shared__ float red[4];
    if (!(tid & 63)) red[tid >> 6] = s;
    __syncthreads();
    if (tid == 0) part[bid] = red[0] + red[1] + red[2] + red[3];
}

__global__ void finalize_scales(const float* __restrict__ part, float* __restrict__ scales) {
    int t = threadIdx.x;                 // 256 threads
    float v1 = part[t];
    float v2 = (t < 64) ? part[256 + t] : 0.f;
    for (int o = 32; o; o >>= 1) { v1 += __shfl_down(v1, o); v2 += __shfl_down(v2, o); }
    __shared__ float r1[4], r2[4];
    int lane = t & 63, wv = t >> 6;
    if (!lane) { r1[wv] = v1; r2[wv] = v2; }
    __syncthreads();
    if (t == 0) {
        scales[0] = (r1[0] + r1[1] + r1[2] + r1[3]) / 786432.0f;   // 1536*512
        scales[1] = (r2[0] + r2[1] + r2[2] + r2[3]) / 262144.0f;   // 512*512
    }
}

// ---------------- merged ternary quantize -> bf16 ----------------
__global__ __launch_bounds__(256) void quant_all(const float* __restrict__ w1,
                                                 const float* __restrict__ w2,
                                                 const float* __restrict__ scp,
                                                 __bf16* __restrict__ o1,
                                                 __bf16* __restrict__ o2) {
    const int bid = blockIdx.x;
    const float* w; __bf16* o; float s; int idx;
    if (bid < 768) { w = w1; o = o1; s = scp[0]; idx = (bid * 256 + threadIdx.x) * 4; }
    else           { w = w2; o = o2; s = scp[1]; idx = ((bid - 768) * 256 + threadIdx.x) * 4; }
    const float inv = 1.f / (s + 1e-6f);
    float4 v = *reinterpret_cast<const float4*>(w + idx);
    o[idx + 0] = (__bf16)(rintf(fminf(1.f, fmaxf(-1.f, v.x * inv))) * s);
    o[idx + 1] = (__bf16)(rintf(fminf(1.f, fmaxf(-1.f, v.y * inv))) * s);
    o[idx + 2] = (__bf16)(rintf(fminf(1.f, fmaxf(-1.f, v.z * inv))) * s);
    o[idx + 3] = (__bf16)(rintf(fminf(1.f, fmaxf(-1.f, v.w * inv))) * s);
}

// ---------------- wave-per-row layernorm (row = 512), output bf16 ----------------
template<typename TIN>
__global__ __launch_bounds__(256) void ln_fast(const TIN* __restrict__ x,
                                               const float* __restrict__ g,
                                               const float* __restrict__ bta,
                                               __bf16* __restrict__ y) {
    const int row = blockIdx.x * 4 + (threadIdx.x >> 6);
    const int lane = threadIdx.x & 63;
    float v[8];
    if constexpr (sizeof(TIN) == 4) {
        const float4* xr = (const float4*)((const float*)x + (size_t)row * DIMM + lane * 8);
        float4 a = xr[0], bq = xr[1];
        v[0] = a.x; v[1] = a.y; v[2] = a.z; v[3] = a.w;
        v[4] = bq.x; v[5] = bq.y; v[6] = bq.z; v[7] = bq.w;
    } else {
        bf16x8 a = *reinterpret_cast<const bf16x8*>((const __bf16*)x + (size_t)row * DIMM + lane * 8);
#pragma unroll
        for (int e = 0; e < 8; ++e) v[e] = (float)a[e];
    }
    float s = 0.f, sq = 0.f;
#pragma unroll
    for (int e = 0; e < 8; ++e) { s += v[e]; sq += v[e] * v[e]; }
    for (int o = 32; o; o >>= 1) { s += __shfl_xor(s, o); sq += __shfl_xor(sq, o); }
    const float mu = s * (1.f / DIMM);
    const float invs = rsqrtf(sq * (1.f / DIMM) - mu * mu + 1e-5f);
    const float4* gp = (const float4*)(g + lane * 8);
    const float4* bp = (const float4*)(bta + lane * 8);
    float4 g0 = gp[0], g1 = gp[1], b0 = bp[0], b1 = bp[1];
    float o_[8] = {
        (v[0] - mu) * invs * g0.x + b0.x, (v[1] - mu) * invs * g0.y + b0.y,
        (v[2] - mu) * invs * g0.z + b0.z, (v[3] - mu) * invs * g0.w + b0.w,
        (v[4] - mu) * invs * g1.x + b1.x, (v[5] - mu) * invs * g1.y + b1.y,
        (v[6] - mu) * invs * g1.z + b1.z, (v[7] - mu) * invs * g1.w + b1.w };
    uint4 st;
    asm("v_cvt_pk_bf16_f32 %0, %1, %2" : "=v"(st.x) : "v"(o_[0]), "v"(o_[1]));
    asm("v_cvt_pk_bf16_f32 %0, %1, %2" : "=v"(st.y) : "v"(o_[2]), "v"(o_[3]));
    asm("v_cvt_pk_bf16_f32 %0, %1, %2" : "=v"(st.z) : "v"(o_[4]), "v"(o_[5]));
    asm("v_cvt_pk_bf16_f32 %0, %1, %2" : "=v"(st.w) : "v"(o_[6]), "v"(o_[7]));
    *reinterpret_cast<uint4*>(y + (size_t)row * DIMM + lane * 8) = st;
}

// ---------------- LDS-staged MFMA GEMM (round-6 exact) ----------------
template<int NCOLS, bool BIAS, bool OUT_F32>
__global__ __launch_bounds__(256) void gemm_lds(const __bf16* __restrict__ A,
                                                const __bf16* __restrict__ Wt,
                                                const float* __restrict__ bias,
                                                __bf16* __restrict__ outb,
                                                float* __restrict__ outf) {
    const int K = DIMM;
    __shared__ __align__(16) __bf16 As[2][4096];
    __shared__ __align__(16) __bf16 Bs[2][4096];

    const int tid = threadIdx.x;
    const int w = tid >> 6, lane = tid & 63;
    const int m = lane & 15, g = lane >> 4;
    const int mi = w >> 1, ni = w & 1;

    const int trow = tid >> 2;
    const int tc = tid & 3;
    const int sc = (tc ^ ((trow >> 1) & 3)) * 8;
    const __bf16* a0 = A  + (size_t)(blockIdx.x * 128 + trow) * K + sc;
    const __bf16* a1 = a0 + (size_t)64 * K;
    const __bf16* b0 = Wt + (size_t)(blockIdx.y * 128 + trow) * K + sc;
    const __bf16* b1 = b0 + (size_t)64 * K;

    f32x4 acc[4][4] = {};

    GLOAD_LDS16(a0, (char*)As[0] + tid * 16);
    GLOAD_LDS16(a1, (char*)As[0] + 4096 + tid * 16);
    GLOAD_LDS16(b0, (char*)Bs[0] + tid * 16);
    GLOAD_LDS16(b1, (char*)Bs[0] + 4096 + tid * 16);

    int cur = 0;
    for (int k0 = 0; k0 < K; k0 += 32) {
        __syncthreads();
        if (k0 + 32 < K) {
            GLOAD_LDS16(a0 + k0 + 32, (char*)As[cur ^ 1] + tid * 16);
            GLOAD_LDS16(a1 + k0 + 32, (char*)As[cur ^ 1] + 4096 + tid * 16);
            GLOAD_LDS16(b0 + k0 + 32, (char*)Bs[cur ^ 1] + tid * 16);
            GLOAD_LDS16(b1 + k0 + 32, (char*)Bs[cur ^ 1] + 4096 + tid * 16);
        }

        const char* Ab = (const char*)As[cur];
        const char* Bb = (const char*)Bs[cur];
        bf16x8 af[4], bfr[4];
#pragma unroll
        for (int i = 0; i < 4; ++i) {
            const int ra = mi * 64 + i * 16 + m;
            af[i] = *reinterpret_cast<const bf16x8*>(Ab + ra * 64 + ((g ^ ((ra >> 1) & 3)) << 4));
        }
#pragma unroll
        for (int j = 0; j < 4; ++j) {
            const int rb = ni * 64 + j * 16 + m;
            bfr[j] = *reinterpret_cast<const bf16x8*>(Bb + rb * 64 + ((g ^ ((rb >> 1) & 3)) << 4));
        }
#pragma unroll
        for (int i = 0; i < 4; ++i)
#pragma unroll
            for (int j = 0; j < 4; ++j)
                acc[i][j] = __builtin_amdgcn_mfma_f32_16x16x32_bf16(af[i], bfr[j], acc[i][j], 0, 0, 0);
        cur ^= 1;
    }

    const int orow0 = blockIdx.x * 128 + mi * 64 + g * 4;
    const int ocol0 = blockIdx.y * 128 + ni * 64;
#pragma unroll
    for (int i = 0; i < 4; ++i)
#pragma unroll
        for (int j = 0; j < 4; ++j)
#pragma unroll
            for (int r = 0; r < 4; ++r) {
                int row = orow0 + i * 16 + r;
                int col = ocol0 + j * 16 + m;
                float v = acc[i][j][r];
                if (BIAS) v += bias[col];
                if (OUT_F32) outf[(size_t)row * NCOLS + col] = v;
                else         outb[(size_t)row * NCOLS + col] = (__bf16)v;
            }
}

// ---------------- MFMA flash attention (round-6 verbatim body) ----------------
// ONLY change vs round 6: grid transposed to (bh=64, qt=8) so linear block id
// % 8 == h -> all 8 q-blocks sharing one (b,h)'s K/V land on the SAME XCD
// (per-XCD K/V working set 2 MB <= 4 MB L2). Pure relabeling, output-identical.
__global__ __launch_bounds__(256, 2) void attn_mfma(const __bf16* __restrict__ qkv,
                                                    __bf16* __restrict__ out) {
    const int qt = blockIdx.y, bh = blockIdx.x;
    const int b = bh >> 3, h = bh & 7;
    const int tid = threadIdx.x;
    const int w = tid >> 6, lane = tid & 63;
    const int g = lane >> 4, m = lane & 15;

    __shared__ __align__(16) __bf16 Kb[4096];      // [64 key][64 d], chunk c at c^(key&7)
    __shared__ __align__(16) __bf16 Vt[4096];      // [64 d][64 key], chunk c at c^((d>>3)^(d&7))
    __shared__ __align__(16) __bf16 Pl[4][2048];   // per-wave [32 q][64 key], chunk c at c^(q&7)

    bf16x8 qf[2][2];
    {
        const __bf16* qp = qkv + (size_t)(b * SEQ + qt * 128 + w * 32 + m) * TRIPLE + h * 64 + g * 8;
#pragma unroll
        for (int hf = 0; hf < 2; ++hf) {
            qf[hf][0] = *reinterpret_cast<const bf16x8*>(qp + (size_t)hf * 16 * TRIPLE);
            qf[hf][1] = *reinterpret_cast<const bf16x8*>(qp + (size_t)hf * 16 * TRIPLE + 32);
#pragma unroll
            for (int e = 0; e < 8; ++e) {
                qf[hf][0][e] = (__bf16)((float)qf[hf][0][e] * 0.125f);
                qf[hf][1][e] = (__bf16)((float)qf[hf][1][e] * 0.125f);
            }
        }
    }

    const int srow = tid >> 3;          // 0..31
    const int sc   = tid & 7;           // 0..7
    const size_t rbase = (size_t)(b * SEQ + srow) * TRIPLE + h * 64 + sc * 8;
    const __bf16* k0s = qkv + rbase + DIMM;
    const __bf16* v0s = qkv + rbase + 2 * DIMM;
    const __bf16* k1s = k0s + (size_t)32 * TRIPLE;
    const __bf16* v1s = v0s + (size_t)32 * TRIPLE;
    const int kstep = 64 * TRIPLE;

    char* kw0 = (char*)Kb + srow * 128 + ((sc ^ (srow & 7)) << 4);
    char* kw1 = kw0 + 32 * 128;
    char* vbp = (char*)Vt;

    f32x4 oa[2][4] = {};
    float mrun[2] = {-1e30f, -1e30f}, lrun[2] = {0.f, 0.f};

    uint4 k0c = *reinterpret_cast<const uint4*>(k0s);
    uint4 k1c = *reinterpret_cast<const uint4*>(k1s);
    uint4 v0c = *reinterpret_cast<const uint4*>(v0s);
    uint4 v1c = *reinterpret_cast<const uint4*>(v1s);
    uint4 k0n = {}, k1n = {}, v0n = {}, v1n = {};

    for (int t = 0; t < 16; ++t) {
        __syncthreads();

        *reinterpret_cast<bf16x8*>(kw0) = *reinterpret_cast<bf16x8*>(&k0c);
        *reinterpret_cast<bf16x8*>(kw1) = *reinterpret_cast<bf16x8*>(&k1c);
        {
            bf16x8 va = *reinterpret_cast<bf16x8*>(&v0c);
            bf16x8 vb = *reinterpret_cast<bf16x8*>(&v1c);
#pragma unroll
            for (int e = 0; e < 8; ++e) {
                const int dro = (sc * 8 + e) * 128;
                const int sw = ((sc ^ e) & 7) << 4;
                *(__bf16*)(vbp + dro + ((srow * 2) ^ sw))        = va[e];
                *(__bf16*)(vbp + dro + (((srow + 32) * 2) ^ sw)) = vb[e];
            }
        }
        __syncthreads();

        if (t < 15) {
            k0n = *reinterpret_cast<const uint4*>(k0s + (size_t)(t + 1) * kstep);
            k1n = *reinterpret_cast<const uint4*>(k1s + (size_t)(t + 1) * kstep);
            v0n = *reinterpret_cast<const uint4*>(v0s + (size_t)(t + 1) * kstep);
            v1n = *reinterpret_cast<const uint4*>(v1s + (size_t)(t + 1) * kstep);
        }

        // ---- S^T = K @ Q^T ----
        const char* kb = (const char*)Kb;
        f32x4 sa[2][4];
#pragma unroll
        for (int hf = 0; hf < 2; ++hf)
#pragma unroll
            for (int i = 0; i < 4; ++i) sa[hf][i] = (f32x4){0.f, 0.f, 0.f, 0.f};
#pragma unroll
        for (int kc = 0; kc < 2; ++kc) {
            const int cp = ((kc * 4 + g) ^ (m & 7)) << 4;
#pragma unroll
            for (int i = 0; i < 4; ++i) {
                bf16x8 kf = *reinterpret_cast<const bf16x8*>(kb + (i * 16 + m) * 128 + cp);
                sa[0][i] = __builtin_amdgcn_mfma_f32_16x16x32_bf16(kf, qf[0][kc], sa[0][i], 0, 0, 0);
                sa[1][i] = __builtin_amdgcn_mfma_f32_16x16x32_bf16(kf, qf[1][kc], sa[1][i], 0, 0, 0);
            }
        }

        // ---- online softmax per half + P pack/store ----
        char* pw = (char*)Pl[w] + m * 128;
        const int psw = (m & 7) << 4;
#pragma unroll
        for (int hf = 0; hf < 2; ++hf) {
            float mx = -1e30f;
#pragma unroll
            for (int i = 0; i < 4; ++i)
#pragma unroll
                for (int r = 0; r < 4; ++r) mx = fmaxf(mx, sa[hf][i][r]);
            mx = fmaxf(mx, __shfl_xor(mx, 16));
            mx = fmaxf(mx, __shfl_xor(mx, 32));
            const float mnew = fmaxf(mrun[hf], mx);
            float p[4][4];
            float ps = 0.f;
#pragma unroll
            for (int i = 0; i < 4; ++i)
#pragma unroll
                for (int r = 0; r < 4; ++r) { p[i][r] = __expf(sa[hf][i][r] - mnew); ps += p[i][r]; }
            ps += __shfl_xor(ps, 16);
            ps += __shfl_xor(ps, 32);
            const float al = __expf(mrun[hf] - mnew);
            mrun[hf] = mnew;
            lrun[hf] = lrun[hf] * al + ps;
#pragma unroll
            for (int i = 0; i < 4; ++i)
#pragma unroll
                for (int r = 0; r < 4; ++r) oa[hf][i][r] *= al;
#pragma unroll
            for (int i = 0; i < 4; ++i) {
                uint2 pk;
                asm("v_cvt_pk_bf16_f32 %0, %1, %2" : "=v"(pk.x) : "v"(p[i][0]), "v"(p[i][1]));
                asm("v_cvt_pk_bf16_f32 %0, %1, %2" : "=v"(pk.y) : "v"(p[i][2]), "v"(p[i][3]));
                *reinterpret_cast<uint2*>(pw + hf * 16 * 128 + ((i * 32 + g * 8) ^ psw)) = pk;
            }
        }

        // ---- P fragments ----
        bf16x8 pf[2][2];
#pragma unroll
        for (int hf = 0; hf < 2; ++hf)
#pragma unroll
            for (int kc = 0; kc < 2; ++kc)
                pf[hf][kc] = *reinterpret_cast<const bf16x8*>(
                    pw + hf * 16 * 128 + ((kc * 64 + g * 16) ^ psw));

        // ---- O^T += V^T @ P^T ----
#pragma unroll
        for (int kc = 0; kc < 2; ++kc)
#pragma unroll
            for (int i = 0; i < 4; ++i) {
                const int sv = ((i * 2 + (m >> 3)) ^ (m & 7)) & 7;
                bf16x8 vf = *reinterpret_cast<const bf16x8*>(
                    vbp + (i * 16 + m) * 128 + (((kc * 4 + g) ^ sv) << 4));
                oa[0][i] = __builtin_amdgcn_mfma_f32_16x16x32_bf16(vf, pf[0][kc], oa[0][i], 0, 0, 0);
                oa[1][i] = __builtin_amdgcn_mfma_f32_16x16x32_bf16(vf, pf[1][kc], oa[1][i], 0, 0, 0);
            }

        k0c = k0n; k1c = k1n; v0c = v0n; v1c = v1n;
    }

#pragma unroll
    for (int hf = 0; hf < 2; ++hf) {
        const float inv = 1.0f / lrun[hf];
        unsigned int* orow = (unsigned int*)(out +
            (size_t)(b * SEQ + qt * 128 + w * 32 + hf * 16 + m) * DIMM + h * 64);
#pragma unroll
        for (int i = 0; i < 4; ++i)
#pragma unroll
            for (int rp = 0; rp < 2; ++rp) {
                float o0 = oa[hf][i][2 * rp] * inv, o1 = oa[hf][i][2 * rp + 1] * inv;
                unsigned int pk;
                asm("v_cvt_pk_bf16_f32 %0, %1, %2" : "=v"(pk) : "v"(o0), "v"(o1));
                orow[i * 8 + g * 2 + rp] = pk;
            }
    }
}

// ---------------- launch ----------------
extern "C" void kernel_launch(void* const* d_in, const int* in_sizes, int n_in,
                              void* d_out, int out_size, void* d_ws, size_t ws_size,
                              hipStream_t stream) {
    const float* x     = (const float*)d_in[0];
    const float* g1    = (const float*)d_in[1];
    const float* b1    = (const float*)d_in[2];
    const float* W_qkv = (const float*)d_in[3];
    const float* g2    = (const float*)d_in[4];
    const float* b2    = (const float*)d_in[5];
    const float* W_out = (const float*)d_in[6];
    const float* b_out = (const float*)d_in[7];
    float* out = (float*)d_out;

    char* ws = (char*)d_ws;
    float* part   = (float*)(ws);                                // 320 floats
    float* scales = (float*)(ws + 2048);
    __bf16* Wq1 = (__bf16*)(ws + 4096);                          // [1536,512]
    __bf16* Wq2 = (__bf16*)(ws + 4096 + 1572864);                // [512,512]
    __bf16* Xln = (__bf16*)(ws + 4096 + 1572864 + 524288);       // [8192,512] (reused for LN2 out)
    __bf16* QKV = (__bf16*)(ws + 4096 + 1572864 + 524288 + 8388608);            // [8192,1536]
    __bf16* AO  = (__bf16*)(ws + 4096 + 1572864 + 524288 + 8388608 + 25165824); // [8192,512]

    absum_all<<<320, 256, 0, stream>>>(W_qkv, W_out, part);
    finalize_scales<<<1, 256, 0, stream>>>(part, scales);
    quant_all<<<1024, 256, 0, stream>>>(W_qkv, W_out, scales, Wq1, Wq2);
    ln_fast<float><<<MROWS / 4, 256, 0, stream>>>(x, g1, b1, Xln);
    gemm_lds<TRIPLE, false, false><<<dim3(64, 12), 256, 0, stream>>>(Xln, Wq1, nullptr, QKV, nullptr);
    attn_mfma<<<dim3(64, 8), 256, 0, stream>>>(QKV, AO);
    ln_fast<__bf16><<<MROWS / 4, 256, 0, stream>>>(AO, g2, b2, Xln);
    gemm_lds<DIMM, true, true><<<dim3(64, 4), 256, 0, stream>>>(Xln, Wq2, b_out, nullptr, out);
}

// Round 13
// 89.820 us; speedup vs baseline: 1.0752x; 1.0004x over previous
//
#include <hip/hip_runtime.h>
#include <hip/hip_bf16.h>

typedef __bf16 bf16x8 __attribute__((ext_vector_type(8)));
typedef float  f32x4  __attribute__((ext_vector_type(4)));

#define SEQ   1024
#define BATCH 8
#define DIMM  512
#define HEADS 8
#define DHEAD 64
#define TRIPLE 1536
#define MROWS (BATCH*SEQ)   // 8192

#define GLOAD_LDS16(g, l) __builtin_amdgcn_global_load_lds( \
    (const __attribute__((address_space(1))) void*)(const void*)(g), \
    (__attribute__((address_space(3))) void*)(void*)(l), 16, 0, 0)

// ---------------- merged |w| partial sums ----------------
__global__ __launch_bounds__(256) void absum_all(const float* __restrict__ w1,
                                                 const float* __restrict__ w2,
                                                 float* __restrict__ part) {
    const int bid = blockIdx.x, tid = threadIdx.x;
    float s = 0.f;
    if (bid < 256) {
        const float4* p = (const float4*)w1;
        for (int i = bid * 256 + tid; i < 196608; i += 65536) {
            float4 v = p[i];
            s += fabsf(v.x) + fabsf(v.y) + fabsf(v.z) + fabsf(v.w);
        }
    } else {
        const float4* p = (const float4*)w2;
        for (int i = (bid - 256) * 256 + tid; i < 65536; i += 16384) {
            float4 v = p[i];
            s += fabsf(v.x) + fabsf(v.y) + fabsf(v.z) + fabsf(v.w);
        }
    }
    for (int o = 32; o; o >>= 1) s += __shfl_down(s, o);
    __shared__ float red[4];
    if (!(tid & 63)) red[tid >> 6] = s;
    __syncthreads();
    if (tid == 0) part[bid] = red[0] + red[1] + red[2] + red[3];
}

// ---------------- ternary quantize -> bf16 (finalize fused: block reduces partials) ----------------
__global__ __launch_bounds__(256) void quant_all(const float* __restrict__ w1,
                                                 const float* __restrict__ w2,
                                                 const float* __restrict__ part,
                                                 __bf16* __restrict__ o1,
                                                 __bf16* __restrict__ o2) {
    const int bid = blockIdx.x, tid = threadIdx.x;
    // block-local deterministic reduction of the relevant partial range
    float acc = 0.f;
    if (bid < 768) acc = part[tid];                       // 256 partials of W_qkv
    else if (tid < 64) acc = part[256 + tid];             // 64 partials of W_out
    for (int o = 32; o; o >>= 1) acc += __shfl_down(acc, o);
    __shared__ float red[4];
    if (!(tid & 63)) red[tid >> 6] = acc;
    __syncthreads();
    const float tot = red[0] + red[1] + red[2] + red[3];
    const float s = (bid < 768) ? tot / 786432.0f : tot / 262144.0f;
    const float inv = 1.f / (s + 1e-6f);

    const float* w; __bf16* o; int idx;
    if (bid < 768) { w = w1; o = o1; idx = (bid * 256 + tid) * 4; }
    else           { w = w2; o = o2; idx = ((bid - 768) * 256 + tid) * 4; }
    float4 v = *reinterpret_cast<const float4*>(w + idx);
    o[idx + 0] = (__bf16)(rintf(fminf(1.f, fmaxf(-1.f, v.x * inv))) * s);
    o[idx + 1] = (__bf16)(rintf(fminf(1.f, fmaxf(-1.f, v.y * inv))) * s);
    o[idx + 2] = (__bf16)(rintf(fminf(1.f, fmaxf(-1.f, v.z * inv))) * s);
    o[idx + 3] = (__bf16)(rintf(fminf(1.f, fmaxf(-1.f, v.w * inv))) * s);
}

// ---------------- wave-per-row layernorm (row = 512), output bf16 ----------------
template<typename TIN>
__global__ __launch_bounds__(256) void ln_fast(const TIN* __restrict__ x,
                                               const float* __restrict__ g,
                                               const float* __restrict__ bta,
                                               __bf16* __restrict__ y) {
    const int row = blockIdx.x * 4 + (threadIdx.x >> 6);
    const int lane = threadIdx.x & 63;
    float v[8];
    if constexpr (sizeof(TIN) == 4) {
        const float4* xr = (const float4*)((const float*)x + (size_t)row * DIMM + lane * 8);
        float4 a = xr[0], bq = xr[1];
        v[0] = a.x; v[1] = a.y; v[2] = a.z; v[3] = a.w;
        v[4] = bq.x; v[5] = bq.y; v[6] = bq.z; v[7] = bq.w;
    } else {
        bf16x8 a = *reinterpret_cast<const bf16x8*>((const __bf16*)x + (size_t)row * DIMM + lane * 8);
#pragma unroll
        for (int e = 0; e < 8; ++e) v[e] = (float)a[e];
    }
    float s = 0.f, sq = 0.f;
#pragma unroll
    for (int e = 0; e < 8; ++e) { s += v[e]; sq += v[e] * v[e]; }
    for (int o = 32; o; o >>= 1) { s += __shfl_xor(s, o); sq += __shfl_xor(sq, o); }
    const float mu = s * (1.f / DIMM);
    const float invs = rsqrtf(sq * (1.f / DIMM) - mu * mu + 1e-5f);
    const float4* gp = (const float4*)(g + lane * 8);
    const float4* bp = (const float4*)(bta + lane * 8);
    float4 g0 = gp[0], g1 = gp[1], b0 = bp[0], b1 = bp[1];
    float o_[8] = {
        (v[0] - mu) * invs * g0.x + b0.x, (v[1] - mu) * invs * g0.y + b0.y,
        (v[2] - mu) * invs * g0.z + b0.z, (v[3] - mu) * invs * g0.w + b0.w,
        (v[4] - mu) * invs * g1.x + b1.x, (v[5] - mu) * invs * g1.y + b1.y,
        (v[6] - mu) * invs * g1.z + b1.z, (v[7] - mu) * invs * g1.w + b1.w };
    uint4 st;
    asm("v_cvt_pk_bf16_f32 %0, %1, %2" : "=v"(st.x) : "v"(o_[0]), "v"(o_[1]));
    asm("v_cvt_pk_bf16_f32 %0, %1, %2" : "=v"(st.y) : "v"(o_[2]), "v"(o_[3]));
    asm("v_cvt_pk_bf16_f32 %0, %1, %2" : "=v"(st.z) : "v"(o_[4]), "v"(o_[5]));
    asm("v_cvt_pk_bf16_f32 %0, %1, %2" : "=v"(st.w) : "v"(o_[6]), "v"(o_[7]));
    *reinterpret_cast<uint4*>(y + (size_t)row * DIMM + lane * 8) = st;
}

// ---------------- LDS-staged MFMA GEMM (round-6 exact) ----------------
template<int NCOLS, bool BIAS, bool OUT_F32>
__global__ __launch_bounds__(256) void gemm_lds(const __bf16* __restrict__ A,
                                                const __bf16* __restrict__ Wt,
                                                const float* __restrict__ bias,
                                                __bf16* __restrict__ outb,
                                                float* __restrict__ outf) {
    const int K = DIMM;
    __shared__ __align__(16) __bf16 As[2][4096];
    __shared__ __align__(16) __bf16 Bs[2][4096];

    const int tid = threadIdx.x;
    const int w = tid >> 6, lane = tid & 63;
    const int m = lane & 15, g = lane >> 4;
    const int mi = w >> 1, ni = w & 1;

    const int trow = tid >> 2;
    const int tc = tid & 3;
    const int sc = (tc ^ ((trow >> 1) & 3)) * 8;
    const __bf16* a0 = A  + (size_t)(blockIdx.x * 128 + trow) * K + sc;
    const __bf16* a1 = a0 + (size_t)64 * K;
    const __bf16* b0 = Wt + (size_t)(blockIdx.y * 128 + trow) * K + sc;
    const __bf16* b1 = b0 + (size_t)64 * K;

    f32x4 acc[4][4] = {};

    GLOAD_LDS16(a0, (char*)As[0] + tid * 16);
    GLOAD_LDS16(a1, (char*)As[0] + 4096 + tid * 16);
    GLOAD_LDS16(b0, (char*)Bs[0] + tid * 16);
    GLOAD_LDS16(b1, (char*)Bs[0] + 4096 + tid * 16);

    int cur = 0;
    for (int k0 = 0; k0 < K; k0 += 32) {
        __syncthreads();
        if (k0 + 32 < K) {
            GLOAD_LDS16(a0 + k0 + 32, (char*)As[cur ^ 1] + tid * 16);
            GLOAD_LDS16(a1 + k0 + 32, (char*)As[cur ^ 1] + 4096 + tid * 16);
            GLOAD_LDS16(b0 + k0 + 32, (char*)Bs[cur ^ 1] + tid * 16);
            GLOAD_LDS16(b1 + k0 + 32, (char*)Bs[cur ^ 1] + 4096 + tid * 16);
        }

        const char* Ab = (const char*)As[cur];
        const char* Bb = (const char*)Bs[cur];
        bf16x8 af[4], bfr[4];
#pragma unroll
        for (int i = 0; i < 4; ++i) {
            const int ra = mi * 64 + i * 16 + m;
            af[i] = *reinterpret_cast<const bf16x8*>(Ab + ra * 64 + ((g ^ ((ra >> 1) & 3)) << 4));
        }
#pragma unroll
        for (int j = 0; j < 4; ++j) {
            const int rb = ni * 64 + j * 16 + m;
            bfr[j] = *reinterpret_cast<const bf16x8*>(Bb + rb * 64 + ((g ^ ((rb >> 1) & 3)) << 4));
        }
#pragma unroll
        for (int i = 0; i < 4; ++i)
#pragma unroll
            for (int j = 0; j < 4; ++j)
                acc[i][j] = __builtin_amdgcn_mfma_f32_16x16x32_bf16(af[i], bfr[j], acc[i][j], 0, 0, 0);
        cur ^= 1;
    }

    const int orow0 = blockIdx.x * 128 + mi * 64 + g * 4;
    const int ocol0 = blockIdx.y * 128 + ni * 64;
#pragma unroll
    for (int i = 0; i < 4; ++i)
#pragma unroll
        for (int j = 0; j < 4; ++j)
#pragma unroll
            for (int r = 0; r < 4; ++r) {
                int row = orow0 + i * 16 + r;
                int col = ocol0 + j * 16 + m;
                float v = acc[i][j][r];
                if (BIAS) v += bias[col];
                if (OUT_F32) outf[(size_t)row * NCOLS + col] = v;
                else         outb[(size_t)row * NCOLS + col] = (__bf16)v;
            }
}

// ---------------- MFMA flash attention, 16 q-rows/wave, 4 blocks/CU ----------------
// grid (64 bh, 16 qt); 256 threads = 4 waves, 64 q-rows/block.
// Body = round-6 verified template with the hf loop removed (hf=0 path only);
// K/V staging code IDENTICAL to round 6 (covers all 64 rows independent of q count).
// lin%8 == h preserved -> same-XCD K/V sharing. 24KB LDS -> 4 blocks/CU.
__global__ __launch_bounds__(256, 4) void attn_mfma(const __bf16* __restrict__ qkv,
                                                    __bf16* __restrict__ out) {
    const int qt = blockIdx.y, bh = blockIdx.x;
    const int b = bh >> 3, h = bh & 7;
    const int tid = threadIdx.x;
    const int w = tid >> 6, lane = tid & 63;
    const int g = lane >> 4, m = lane & 15;

    __shared__ __align__(16) __bf16 Kb[4096];      // [64 key][64 d], chunk c at c^(key&7)
    __shared__ __align__(16) __bf16 Vt[4096];      // [64 d][64 key], chunk c at c^((d>>3)^(d&7))
    __shared__ __align__(16) __bf16 Pl[4][1024];   // per-wave [16 q][64 key], chunk c at c^(q&7)

    // Q fragments: qf[kc] = Q[q = m][d = kc*32 + g*8 + j], *0.125 (exact in bf16)
    bf16x8 qf[2];
    {
        const __bf16* qp = qkv + (size_t)(b * SEQ + qt * 64 + w * 16 + m) * TRIPLE + h * 64 + g * 8;
        qf[0] = *reinterpret_cast<const bf16x8*>(qp);
        qf[1] = *reinterpret_cast<const bf16x8*>(qp + 32);
#pragma unroll
        for (int e = 0; e < 8; ++e) {
            qf[0][e] = (__bf16)((float)qf[0][e] * 0.125f);
            qf[1][e] = (__bf16)((float)qf[1][e] * 0.125f);
        }
    }

    // staging (round-6 verbatim): thread -> rows {srow, srow+32}, d-chunk sc
    const int srow = tid >> 3;          // 0..31
    const int sc   = tid & 7;           // 0..7
    const size_t rbase = (size_t)(b * SEQ + srow) * TRIPLE + h * 64 + sc * 8;
    const __bf16* k0s = qkv + rbase + DIMM;
    const __bf16* v0s = qkv + rbase + 2 * DIMM;
    const __bf16* k1s = k0s + (size_t)32 * TRIPLE;
    const __bf16* v1s = v0s + (size_t)32 * TRIPLE;
    const int kstep = 64 * TRIPLE;

    char* kw0 = (char*)Kb + srow * 128 + ((sc ^ (srow & 7)) << 4);
    char* kw1 = kw0 + 32 * 128;
    char* vbp = (char*)Vt;

    f32x4 oa[4] = {};
    float mrun = -1e30f, lrun = 0.f;

    uint4 k0c = *reinterpret_cast<const uint4*>(k0s);
    uint4 k1c = *reinterpret_cast<const uint4*>(k1s);
    uint4 v0c = *reinterpret_cast<const uint4*>(v0s);
    uint4 v1c = *reinterpret_cast<const uint4*>(v1s);
    uint4 k0n = {}, k1n = {}, v0n = {}, v1n = {};

    for (int t = 0; t < 16; ++t) {
        __syncthreads();

        *reinterpret_cast<bf16x8*>(kw0) = *reinterpret_cast<bf16x8*>(&k0c);
        *reinterpret_cast<bf16x8*>(kw1) = *reinterpret_cast<bf16x8*>(&k1c);
        {
            bf16x8 va = *reinterpret_cast<bf16x8*>(&v0c);
            bf16x8 vb = *reinterpret_cast<bf16x8*>(&v1c);
#pragma unroll
            for (int e = 0; e < 8; ++e) {
                const int dro = (sc * 8 + e) * 128;
                const int sw = ((sc ^ e) & 7) << 4;
                *(__bf16*)(vbp + dro + ((srow * 2) ^ sw))        = va[e];
                *(__bf16*)(vbp + dro + (((srow + 32) * 2) ^ sw)) = vb[e];
            }
        }
        __syncthreads();

        if (t < 15) {
            k0n = *reinterpret_cast<const uint4*>(k0s + (size_t)(t + 1) * kstep);
            k1n = *reinterpret_cast<const uint4*>(k1s + (size_t)(t + 1) * kstep);
            v0n = *reinterpret_cast<const uint4*>(v0s + (size_t)(t + 1) * kstep);
            v1n = *reinterpret_cast<const uint4*>(v1s + (size_t)(t + 1) * kstep);
        }

        // ---- S^T = K @ Q^T ----
        const char* kb = (const char*)Kb;
        f32x4 sa[4];
#pragma unroll
        for (int i = 0; i < 4; ++i) sa[i] = (f32x4){0.f, 0.f, 0.f, 0.f};
#pragma unroll
        for (int kc = 0; kc < 2; ++kc) {
            const int cp = ((kc * 4 + g) ^ (m & 7)) << 4;
#pragma unroll
            for (int i = 0; i < 4; ++i) {
                bf16x8 kf = *reinterpret_cast<const bf16x8*>(kb + (i * 16 + m) * 128 + cp);
                sa[i] = __builtin_amdgcn_mfma_f32_16x16x32_bf16(kf, qf[kc], sa[i], 0, 0, 0);
            }
        }

        // ---- online softmax + P pack/store ----
        char* pw = (char*)Pl[w] + m * 128;
        const int psw = (m & 7) << 4;
        {
            float mx = -1e30f;
#pragma unroll
            for (int i = 0; i < 4; ++i)
#pragma unroll
                for (int r = 0; r < 4; ++r) mx = fmaxf(mx, sa[i][r]);
            mx = fmaxf(mx, __shfl_xor(mx, 16));
            mx = fmaxf(mx, __shfl_xor(mx, 32));
            const float mnew = fmaxf(mrun, mx);
            float p[4][4];
            float ps = 0.f;
#pragma unroll
            for (int i = 0; i < 4; ++i)
#pragma unroll
                for (int r = 0; r < 4; ++r) { p[i][r] = __expf(sa[i][r] - mnew); ps += p[i][r]; }
            ps += __shfl_xor(ps, 16);
            ps += __shfl_xor(ps, 32);
            const float al = __expf(mrun - mnew);
            mrun = mnew;
            lrun = lrun * al + ps;
#pragma unroll
            for (int i = 0; i < 4; ++i)
#pragma unroll
                for (int r = 0; r < 4; ++r) oa[i][r] *= al;
#pragma unroll
            for (int i = 0; i < 4; ++i) {
                uint2 pk;
                asm("v_cvt_pk_bf16_f32 %0, %1, %2" : "=v"(pk.x) : "v"(p[i][0]), "v"(p[i][1]));
                asm("v_cvt_pk_bf16_f32 %0, %1, %2" : "=v"(pk.y) : "v"(p[i][2]), "v"(p[i][3]));
                *reinterpret_cast<uint2*>(pw + ((i * 32 + g * 8) ^ psw)) = pk;
            }
        }

        // ---- P fragments ----
        bf16x8 pf[2];
#pragma unroll
        for (int kc = 0; kc < 2; ++kc)
            pf[kc] = *reinterpret_cast<const bf16x8*>(pw + ((kc * 64 + g * 16) ^ psw));

        // ---- O^T += V^T @ P^T ----
#pragma unroll
        for (int kc = 0; kc < 2; ++kc)
#pragma unroll
            for (int i = 0; i < 4; ++i) {
                const int sv = ((i * 2 + (m >> 3)) ^ (m & 7)) & 7;
                bf16x8 vf = *reinterpret_cast<const bf16x8*>(
                    vbp + (i * 16 + m) * 128 + (((kc * 4 + g) ^ sv) << 4));
                oa[i] = __builtin_amdgcn_mfma_f32_16x16x32_bf16(vf, pf[kc], oa[i], 0, 0, 0);
            }

        k0c = k0n; k1c = k1n; v0c = v0n; v1c = v1n;
    }

    // ---- epilogue ----
    const float inv = 1.0f / lrun;
    unsigned int* orow = (unsigned int*)(out +
        (size_t)(b * SEQ + qt * 64 + w * 16 + m) * DIMM + h * 64);
#pragma unroll
    for (int i = 0; i < 4; ++i)
#pragma unroll
        for (int rp = 0; rp < 2; ++rp) {
            float o0 = oa[i][2 * rp] * inv, o1 = oa[i][2 * rp + 1] * inv;
            unsigned int pk;
            asm("v_cvt_pk_bf16_f32 %0, %1, %2" : "=v"(pk) : "v"(o0), "v"(o1));
            orow[i * 8 + g * 2 + rp] = pk;
        }
}

// ---------------- launch ----------------
extern "C" void kernel_launch(void* const* d_in, const int* in_sizes, int n_in,
                              void* d_out, int out_size, void* d_ws, size_t ws_size,
                              hipStream_t stream) {
    const float* x     = (const float*)d_in[0];
    const float* g1    = (const float*)d_in[1];
    const float* b1    = (const float*)d_in[2];
    const float* W_qkv = (const float*)d_in[3];
    const float* g2    = (const float*)d_in[4];
    const float* b2    = (const float*)d_in[5];
    const float* W_out = (const float*)d_in[6];
    const float* b_out = (const float*)d_in[7];
    float* out = (float*)d_out;

    char* ws = (char*)d_ws;
    float* part   = (float*)(ws);                                // 320 floats
    __bf16* Wq1 = (__bf16*)(ws + 4096);                          // [1536,512]
    __bf16* Wq2 = (__bf16*)(ws + 4096 + 1572864);                // [512,512]
    __bf16* Xln = (__bf16*)(ws + 4096 + 1572864 + 524288);       // [8192,512] (reused for LN2 out)
    __bf16* QKV = (__bf16*)(ws + 4096 + 1572864 + 524288 + 8388608);            // [8192,1536]
    __bf16* AO  = (__bf16*)(ws + 4096 + 1572864 + 524288 + 8388608 + 25165824); // [8192,512]

    absum_all<<<320, 256, 0, stream>>>(W_qkv, W_out, part);
    quant_all<<<1024, 256, 0, stream>>>(W_qkv, W_out, part, Wq1, Wq2);
    ln_fast<float><<<MROWS / 4, 256, 0, stream>>>(x, g1, b1, Xln);
    gemm_lds<TRIPLE, false, false><<<dim3(64, 12), 256, 0, stream>>>(Xln, Wq1, nullptr, QKV, nullptr);
    attn_mfma<<<dim3(64, 16), 256, 0, stream>>>(QKV, AO);
    ln_fast<__bf16><<<MROWS / 4, 256, 0, stream>>>(AO, g2, b2, Xln);
    gemm_lds<DIMM, true, true><<<dim3(64, 4), 256, 0, stream>>>(Xln, Wq2, b_out, nullptr, out);
}